// Round 4
// baseline (220.451 us; speedup 1.0000x reference)
//
#include <hip/hip_runtime.h>
#include <math.h>

typedef unsigned short u16;
typedef unsigned int u32;
typedef __attribute__((ext_vector_type(4))) float f32x4;
typedef __attribute__((ext_vector_type(8))) short bf16x8;

#define B_ 2
#define T_ 2048
#define H_ 16
#define HID 1024
#define NQKV 3072
#define M_ 4096
#define SCALE_Q 0.18033688011112042f /* 0.125 * log2(e): softmax done in exp2 domain */

__device__ __forceinline__ u16 f2bf(float f) {
  union { float f; unsigned u; } v; v.f = f;
  unsigned r = v.u + 0x7FFFu + ((v.u >> 16) & 1u);
  return (u16)(r >> 16);
}
__device__ __forceinline__ float bf2f(u16 u) {
  union { unsigned u; float f; } v; v.u = ((unsigned)u) << 16; return v.f;
}
__device__ __forceinline__ u32 cvt_pk_bf16(float lo, float hi) {
  u32 r;
  asm("v_cvt_pk_bf16_f32 %0, %1, %2" : "=v"(r) : "v"(lo), "v"(hi));
  return r;
}
__device__ __forceinline__ float fexp2(float x) { return __builtin_amdgcn_exp2f(x); }

// async global->LDS, 16B per lane; LDS dest = wave-uniform base + lane*16
__device__ __forceinline__ void gload16(const void* g, void* l) {
  __builtin_amdgcn_global_load_lds((const __attribute__((address_space(1))) void*)g,
                                   (__attribute__((address_space(3))) void*)l, 16, 0, 0);
}

// ---------------- prep: rope table + 3x fp32->bf16 convert, fused ----------------
__global__ void prep(const float* __restrict__ x, const float* __restrict__ qkv_w,
                     const float* __restrict__ out_w, u16* __restrict__ xb,
                     u16* __restrict__ wqkv, u16* __restrict__ wout, float* __restrict__ tab) {
  int bid = blockIdx.x;
  if (bid < 128) {  // rope table: tab[t*16+f] = {cos, sin}
    int i = bid * 256 + threadIdx.x;
    int tpos = i >> 4, f = i & 15;
    float ang = (float)tpos * exp2f(-(float)f * 0.83048202372184058696f);
    float s, c;
    sincosf(ang, &s, &c);
    tab[i * 2] = c;
    tab[i * 2 + 1] = s;
    return;
  }
  bid -= 128;
  const float* in;
  u16* out;
  if (bid < 4096) { in = x; out = xb; }
  else if (bid < 7168) { bid -= 4096; in = qkv_w; out = wqkv; }
  else { bid -= 7168; in = out_w; out = wout; }
  int i = bid * 256 + threadIdx.x;
  float4 v = ((const float4*)in)[i];
  uint2 o;
  o.x = (unsigned)f2bf(v.x) | ((unsigned)f2bf(v.y) << 16);
  o.y = (unsigned)f2bf(v.z) | ((unsigned)f2bf(v.w) << 16);
  ((uint2*)out)[i] = o;
}

// ---------------- NT GEMM, dbuf-prefetch: C = A.Bt^T + bias ----------------
// A:[M][K], Bt:[N][K] bf16. Tile BM x 128, 4 waves as WROWS x (4/WROWS).
template<int BM, int BK, int WROWS, int OUT_BF16>
__global__ __launch_bounds__(256) void gemm_nt(const u16* __restrict__ A,
    const u16* __restrict__ Bt, const float* __restrict__ bias,
    void* __restrict__ outp, int N, int K)
{
  constexpr int WCOLS = 4 / WROWS;
  constexpr int MI = BM / WROWS / 16;
  constexpr int NI = 128 / WCOLS / 16;
  constexpr int RPG = 512 / BK;   // rows per 1KB wave-gload
  constexpr int GA = BM / RPG / 4;   // A gloads per wave
  constexpr int GB = 128 / RPG / 4;  // B gloads per wave
  __shared__ u16 lsA[2][BM * BK];
  __shared__ u16 lsB[2][128 * BK];
  const int t = threadIdx.x;
  const int l = t & 63, w = t >> 6;
  const int wm = (w / WCOLS) * (BM / WROWS);
  const int wn = (w % WCOLS) * (128 / WCOLS);
  const int lr = l & 15, lg = l >> 4;
  const long bm = (long)blockIdx.y * BM, bn = (long)blockIdx.x * 128;

  f32x4 acc[MI][NI];
#pragma unroll
  for (int i = 0; i < MI; i++)
#pragma unroll
    for (int j = 0; j < NI; j++) acc[i][j] = (f32x4){0.f, 0.f, 0.f, 0.f};

  const int srow = l / (BK / 8);
  const int sko = (l % (BK / 8)) * 8;
  const u16* Ab = A + (bm + srow) * (long)K + sko;
  const u16* Bb = Bt + (bn + srow) * (long)K + sko;

  auto stage = [&](int buf, int k0) {
#pragma unroll
    for (int g = 0; g < GA; g++)
      gload16(Ab + (long)((w * GA + g) * RPG) * K + k0, &lsA[buf][(w * GA + g) * 512]);
#pragma unroll
    for (int g = 0; g < GB; g++)
      gload16(Bb + (long)((w * GB + g) * RPG) * K + k0, &lsB[buf][(w * GB + g) * 512]);
  };

  stage(0, 0);
  __syncthreads();  // drains vmcnt(0): tile 0 landed
  int cur = 0;
  for (int k0 = 0; k0 < K; k0 += BK) {
    if (k0 + BK < K) stage(cur ^ 1, k0 + BK);  // prefetch overlaps compute
    __builtin_amdgcn_s_setprio(1);
#pragma unroll
    for (int kb = 0; kb < BK / 32; kb++) {
      bf16x8 af[MI], bfv[NI];
#pragma unroll
      for (int mi = 0; mi < MI; mi++)
        af[mi] = *(const bf16x8*)&lsA[cur][(wm + mi * 16 + lr) * BK + kb * 32 + lg * 8];
#pragma unroll
      for (int ni = 0; ni < NI; ni++)
        bfv[ni] = *(const bf16x8*)&lsB[cur][(wn + ni * 16 + lr) * BK + kb * 32 + lg * 8];
#pragma unroll
      for (int mi = 0; mi < MI; mi++)
#pragma unroll
        for (int ni = 0; ni < NI; ni++)
          acc[mi][ni] = __builtin_amdgcn_mfma_f32_16x16x32_bf16(af[mi], bfv[ni], acc[mi][ni], 0, 0, 0);
    }
    __builtin_amdgcn_s_setprio(0);
    __syncthreads();  // vmcnt(0)+barrier: prefetch landed, reads done before overwrite
    cur ^= 1;
  }
#pragma unroll
  for (int mi = 0; mi < MI; mi++)
#pragma unroll
    for (int ni = 0; ni < NI; ni++) {
      long row = bm + wm + mi * 16 + lg * 4;
      long col = bn + wn + ni * 16 + lr;
      float bv = bias[col];
#pragma unroll
      for (int r = 0; r < 4; r++) {
        float v = acc[mi][ni][r] + bv;
        if (OUT_BF16) ((u16*)outp)[(row + r) * (long)N + col] = f2bf(v);
        else          ((float*)outp)[(row + r) * (long)N + col] = v;
      }
    }
}

// ---------------- post_qkv: RoPE(q,k) + V transpose, fused ----------------
// blocks [0,256): rope; blocks [256,1280): v_trans
__global__ __launch_bounds__(256) void post_qkv(const u16* __restrict__ qkv,
    const float* __restrict__ tab, u16* __restrict__ Q, u16* __restrict__ K,
    u16* __restrict__ Vt) {
  __shared__ u16 ls[64 * 72];
  const int bid = blockIdx.x;
  if (bid < 256) {
    int idx = bid * 256 + threadIdx.x;  // one thread per (m, h)
    int h = idx & 15;
    int m = idx >> 4;
    int tpos = m & (T_ - 1);
    int b = m >> 11;
    const u16* qr = qkv + (long)m * NQKV + h * 64;
    alignas(16) u16 qv[64];
    alignas(16) u16 kv[64];
#pragma unroll
    for (int c = 0; c < 8; c++) {
      *(int4*)&qv[c * 8] = *(const int4*)&qr[c * 8];
      *(int4*)&kv[c * 8] = *(const int4*)&qr[1024 + c * 8];
    }
#pragma unroll
    for (int i = 0; i < 16; i++) {
      float c = tab[(tpos * 16 + i) * 2];
      float s = tab[(tpos * 16 + i) * 2 + 1];
      float q1 = bf2f(qv[2 * i]), q2 = bf2f(qv[2 * i + 1]);
      qv[2 * i]     = f2bf((q1 * c - q2 * s) * SCALE_Q);
      qv[2 * i + 1] = f2bf((q1 * s + q2 * c) * SCALE_Q);
      float k1 = bf2f(kv[2 * i]), k2 = bf2f(kv[2 * i + 1]);
      kv[2 * i]     = f2bf(k1 * c - k2 * s);
      kv[2 * i + 1] = f2bf(k1 * s + k2 * c);
    }
#pragma unroll
    for (int j = 32; j < 64; j++) qv[j] = f2bf(bf2f(qv[j]) * SCALE_Q);
    long ob = ((long)(b * 16 + h) * T_ + tpos) * 64;
#pragma unroll
    for (int c = 0; c < 8; c++) {
      *(int4*)&Q[ob + c * 8] = *(int4*)&qv[c * 8];
      *(int4*)&K[ob + c * 8] = *(int4*)&kv[c * 8];
    }
  } else {
    int id2 = bid - 256;
    int tt = id2 & 31, bh = id2 >> 5;
    int b = bh >> 4, h = bh & 15;
    int t = threadIdx.x;
    for (int c = t; c < 512; c += 256) {
      int row = c >> 3, off = (c & 7) * 8;
      *(int4*)&ls[row * 72 + off] =
          *(const int4*)&qkv[((long)(b * T_ + tt * 64 + row)) * NQKV + 2048 + h * 64 + off];
    }
    __syncthreads();
    for (int c = t; c < 512; c += 256) {
      int d = c >> 3, toff = (c & 7) * 8;
      alignas(16) u16 tmp[8];
#pragma unroll
      for (int j = 0; j < 8; j++) tmp[j] = ls[(toff + j) * 72 + d];
      *(int4*)&Vt[((long)(bh * 64 + d)) * T_ + tt * 64 + toff] = *(int4*)tmp;
    }
  }
}

// ---------------- causal flash attention, swapped-QK^T, 8-wave blocks ----------------
// 512 blocks (heavy q-strips first), 8 waves; wave w owns q-rows [qs*128+w*16, +16).
// Lane (lr,lg): q = qbase+lr (per-lane softmax state), holds k-rows lg*4..+3 per 16-tile.
__global__ __launch_bounds__(512, 4) void fattn(const u16* __restrict__ Q, const u16* __restrict__ Kp,
                                                const u16* __restrict__ V, u16* __restrict__ O) {
  const int id = blockIdx.x;
  const int qs = 15 - (id >> 5);  // heavy strips dispatched first
  const int bh = id & 31;         // XCD = bh%8 -> each head's K/V stays in one L2
  __shared__ u16 lsK[2][64 * 64];  // [krow][d], XOR swizzle: u16 chunk ^= (row&7)
  __shared__ u16 lsV[2][64 * 64];  // [d][k], same swizzle
  __shared__ u32 lsP[8][16 * 36];  // per-wave P round-trip
  const int t = threadIdx.x, l = t & 63, w = t >> 6;  // w in 0..7
  const int lr = l & 15, lg = l >> 4;
  const u16* Qb = Q + (long)bh * T_ * 64;
  const u16* Kb = Kp + (long)bh * T_ * 64;
  const u16* Vb = V + (long)bh * 64 * T_;
  u32* lsPw = lsP[w];
  const int qbase = qs * 128 + w * 16;  // wave's first q-row (global)
  const int qg = qbase + lr;            // this lane's q

  bf16x8 aq[2];  // B-frag: Q rows (pre-scaled by 0.125*log2e)
#pragma unroll
  for (int ks = 0; ks < 2; ks++)
    aq[ks] = *(const bf16x8*)&Qb[(long)qg * 64 + ks * 32 + lg * 8];

  f32x4 o[4];
#pragma unroll
  for (int di = 0; di < 4; di++) o[di] = (f32x4){0.f, 0.f, 0.f, 0.f};
  float mrow = -1e30f, lrow = 0.f;

  // staging: each wave 1 K-gload + 1 V-gload (8 rows x 128B each), pre-swizzled source.
  const int srow = l >> 3;
  const int scx = ((l & 7) ^ srow) * 8;
  const long kgo = (long)(8 * w + srow) * 64 + scx;
  const long vgo = (long)(8 * w + srow) * T_ + scx;

  gload16(Kb + kgo, &lsK[0][w * 512]);
  gload16(Vb + vgo, &lsV[0][w * 512]);
  __syncthreads();  // vmcnt(0) drain: tile 0 ready

  int cur = 0;
  const int ktmax = 2 * qs + 1;
  for (int kt = 0; kt <= ktmax; kt++) {
    if (kt < ktmax) {  // prefetch next tile into other buffer
      gload16(Kb + (long)(kt + 1) * 4096 + kgo, &lsK[cur ^ 1][w * 512]);
      gload16(Vb + (long)(kt + 1) * 64 + vgo, &lsV[cur ^ 1][w * 512]);
    }
    const int kbase = kt * 64;
    if (kbase <= qbase + 15) {  // tile has unmasked rows for this wave
      // S^T = K . Q^T : s[ji] rows k=ji*16+lg*4+r, col q=lr
      f32x4 s[4];
#pragma unroll
      for (int ji = 0; ji < 4; ji++) s[ji] = (f32x4){0.f, 0.f, 0.f, 0.f};
      __builtin_amdgcn_s_setprio(1);
#pragma unroll
      for (int ks = 0; ks < 2; ks++)
#pragma unroll
        for (int ji = 0; ji < 4; ji++) {
          int row = ji * 16 + lr;
          bf16x8 kf = *(const bf16x8*)&lsK[cur][row * 64 + ((ks * 32 + lg * 8) ^ ((row & 7) * 8))];
          s[ji] = __builtin_amdgcn_mfma_f32_16x16x32_bf16(kf, aq[ks], s[ji], 0, 0, 0);
        }
      __builtin_amdgcn_s_setprio(0);

      if (kbase + 63 > qbase) {  // partially-masked tile
#pragma unroll
        for (int ji = 0; ji < 4; ji++)
#pragma unroll
          for (int r = 0; r < 4; r++)
            if (kbase + ji * 16 + lg * 4 + r > qg) s[ji][r] = -1e30f;
      }

      // max: pairwise tree over 16 in-lane + 2 shfl (4 lanes share q)
      float m01 = fmaxf(fmaxf(s[0][0], s[0][1]), fmaxf(s[0][2], s[0][3]));
      float m23 = fmaxf(fmaxf(s[1][0], s[1][1]), fmaxf(s[1][2], s[1][3]));
      float m45 = fmaxf(fmaxf(s[2][0], s[2][1]), fmaxf(s[2][2], s[2][3]));
      float m67 = fmaxf(fmaxf(s[3][0], s[3][1]), fmaxf(s[3][2], s[3][3]));
      float mx = fmaxf(fmaxf(m01, m23), fmaxf(m45, m67));
      mx = fmaxf(mx, __shfl_xor(mx, 16, 64));
      mx = fmaxf(mx, __shfl_xor(mx, 32, 64));

      if (__any(mx - mrow > 8.f)) {  // defer-max (T13)
        float newm = fmaxf(mrow, mx);
        float sf = fexp2(mrow - newm);
        mrow = newm;
        lrow *= sf;
#pragma unroll
        for (int r = 0; r < 4; r++) {
          float sfb = __shfl(sf, lg * 4 + r, 64);
#pragma unroll
          for (int di = 0; di < 4; di++) o[di][r] *= sfb;
        }
      }

      float p[16];
      u32 pd[8];
#pragma unroll
      for (int ji = 0; ji < 4; ji++)
#pragma unroll
        for (int r = 0; r < 4; r++) p[ji * 4 + r] = fexp2(s[ji][r] - mrow);
#pragma unroll
      for (int jj = 0; jj < 8; jj++) pd[jj] = cvt_pk_bf16(p[2 * jj], p[2 * jj + 1]);
      // sum tree
      float rs = 0.f;
      {
        float a0 = (p[0] + p[1]) + (p[2] + p[3]);
        float a1 = (p[4] + p[5]) + (p[6] + p[7]);
        float a2 = (p[8] + p[9]) + (p[10] + p[11]);
        float a3 = (p[12] + p[13]) + (p[14] + p[15]);
        rs = (a0 + a1) + (a2 + a3);
      }
      rs += __shfl_xor(rs, 16, 64);
      rs += __shfl_xor(rs, 32, 64);
      lrow += rs;

      // P -> per-wave LDS (packed b64 stores), read back as PV A-frags
#pragma unroll
      for (int ji = 0; ji < 4; ji++)
        *(uint2*)&lsPw[lr * 36 + ji * 8 + lg * 2] = make_uint2(pd[2 * ji], pd[2 * ji + 1]);
      __builtin_amdgcn_s_setprio(1);
#pragma unroll
      for (int js = 0; js < 2; js++) {
        bf16x8 pa = *(const bf16x8*)&lsPw[lr * 36 + js * 16 + lg * 4];
#pragma unroll
        for (int di = 0; di < 4; di++) {
          int drow = di * 16 + lr;
          bf16x8 vb = *(const bf16x8*)&lsV[cur][drow * 64 + ((js * 32 + lg * 8) ^ ((drow & 7) * 8))];
          o[di] = __builtin_amdgcn_mfma_f32_16x16x32_bf16(pa, vb, o[di], 0, 0, 0);
        }
      }
      __builtin_amdgcn_s_setprio(0);
    }

    if (kt < ktmax) __syncthreads();  // drain prefetch + guard buffer reuse
    cur ^= 1;
  }

  const int b = bh >> 4, h = bh & 15;
  float inv = 1.f / lrow;
#pragma unroll
  for (int r = 0; r < 4; r++) {
    float invb = __shfl(inv, lg * 4 + r, 64);
#pragma unroll
    for (int di = 0; di < 4; di++) {
      long rowt = (long)(b * T_ + qbase + lg * 4 + r);
      O[rowt * 1024 + h * 64 + di * 16 + lr] = f2bf(o[di][r] * invb);
    }
  }
}

extern "C" void kernel_launch(void* const* d_in, const int* in_sizes, int n_in,
                              void* d_out, int out_size, void* d_ws, size_t ws_size,
                              hipStream_t stream) {
  (void)in_sizes; (void)n_in; (void)out_size; (void)ws_size;
  const float* x     = (const float*)d_in[0];
  // d_in[1] = mask: deterministic causal triu — applied analytically, not read.
  const float* qkv_w = (const float*)d_in[2];
  const float* qkv_b = (const float*)d_in[3];
  const float* out_w = (const float*)d_in[4];
  const float* out_b = (const float*)d_in[5];
  char* ws = (char*)d_ws;
  size_t off = 0;
  auto alloc = [&](size_t n) { void* p = ws + off; off += (n + 255) & ~(size_t)255; return p; };
  u16*   xb    = (u16*)alloc((size_t)M_ * HID * 2);
  u16*   wqkv  = (u16*)alloc((size_t)NQKV * HID * 2);
  u16*   wout  = (u16*)alloc((size_t)HID * HID * 2);
  u16*   qkvb  = (u16*)alloc((size_t)M_ * NQKV * 2);
  u16*   Qb    = (u16*)alloc((size_t)M_ * HID * 2);
  u16*   Kb    = (u16*)alloc((size_t)M_ * HID * 2);
  u16*   Vtb   = (u16*)alloc((size_t)M_ * HID * 2);
  u16*   attnb = (u16*)alloc((size_t)M_ * HID * 2);
  float* tab   = (float*)alloc((size_t)T_ * 16 * 2 * 4);

  prep<<<8320, 256, 0, stream>>>(x, qkv_w, out_w, xb, wqkv, wout, tab);
  gemm_nt<128, 32, 2, 1><<<dim3(NQKV / 128, M_ / 128), 256, 0, stream>>>(xb, wqkv, qkv_b, qkvb, NQKV, HID);
  post_qkv<<<1280, 256, 0, stream>>>(qkvb, tab, Qb, Kb, Vtb);
  fattn<<<512, 512, 0, stream>>>(Qb, Kb, Vtb, attnb);
  gemm_nt<128, 64, 2, 0><<<dim3(HID / 128, M_ / 128), 256, 0, stream>>>(attnb, wout, out_b, (float*)d_out, HID, HID);
}